// Round 15
// baseline (257.629 us; speedup 1.0000x reference)
//
#include <hip/hip_runtime.h>
#include <math.h>

// Problem constants (fixed by setup_inputs)
#define B_   4
#define T_   2048
#define D_   768
#define M_   8192      // B*T
#define GD_  256
#define NH_  4
#define HD_  64

typedef short  s16x8 __attribute__((ext_vector_type(8)));
typedef __bf16 bfx8  __attribute__((ext_vector_type(8)));
typedef float  fx4   __attribute__((ext_vector_type(4)));

#define LOG2E 1.44269504088896f
#define QSCALE (0.125f * LOG2E)      // folded into Q at qkv-GEMM epilogue

__device__ __forceinline__ short f2bf(float f) {   // round-to-nearest-even
  union { float f; unsigned u; } v; v.f = f;
  unsigned r = v.u + 0x7fffu + ((v.u >> 16) & 1u);
  return (short)(r >> 16);
}

__device__ __forceinline__ unsigned cvt_pk_bf16(float lo, float hi) {
  // dword = { bf16(lo) in [15:0], bf16(hi) in [31:16] }
  unsigned r;
  asm("v_cvt_pk_bf16_f32 %0, %1, %2" : "=v"(r) : "v"(lo), "v"(hi));
  return r;
}

// async global -> LDS, 16 B per lane; lds base must be wave-uniform,
// global address is per-lane (pre-swizzled source pattern).
__device__ __forceinline__ void gload16(const void* g, void* l) {
  __builtin_amdgcn_global_load_lds(
      (const __attribute__((address_space(1))) unsigned int*)g,
      (__attribute__((address_space(3))) unsigned int*)l, 16, 0, 0);
}

struct PW { const short* p0; const short* p1; const short* p2; };
struct PB { const float* p0; const float* p1; const float* p2; };
__device__ __forceinline__ const short* selw(const PW& s, int z) {
  return z == 0 ? s.p0 : (z == 1 ? s.p1 : s.p2);
}
__device__ __forceinline__ const float* selb(const PB& s, int z) {
  return z == 0 ? s.p0 : (z == 1 ? s.p1 : s.p2);
}

// ---------------------------------------------------------------------------
// bf16 MFMA GEMM v5: BM templated, BN=128, BK=64, 4 waves (2x2), wave tile
// (BM/2)x64, acc [BM/32][4], bijective XCD swizzle, XOR-swizzled LDS.
// Non-AT: global_load_lds + dbuf + counted vmcnt.  AT: reg-staged,
// counted-barrier pipeline (kept for generality; no longer used -- x is
// pre-converted to bf16 by cvt_kernel so gemm1 takes the non-AT path).
// MODE: 0 plain | 1 qkv | 2 u^T.
// ---------------------------------------------------------------------------
template<int AT, int OBF, int MODE, int BM>
__global__ __launch_bounds__(256) void gemm_mfma(
    const void* __restrict__ Avoid, long sA, int lda,
    PW Wp, PB Bp, int K,
    void* __restrict__ C, long sC, int ldc,
    void* __restrict__ xtra)
{
  constexpr int NF = BM / 32;        // A row-frags per wave (2 or 4)
  constexpr int WTM = BM / 2;        // wave tile M
  __shared__ short As[2][BM * 64];
  __shared__ short Bs[AT ? 1 : 2][128 * 64];

  const int z = blockIdx.z;
  const short* Ab16 = (const short*)Avoid + (long)z * sA;
  const float* Ab32 = (const float*)Avoid + (long)z * sA;
  const short* Wb = selw(Wp, z);
  const float* bb = selb(Bp, z);

  // flatten + bijective XCD swizzle (nwg need not be %8)
  const int nx = gridDim.x, nwg = nx * gridDim.y;
  const int orig = blockIdx.y * nx + blockIdx.x;
  const int xcd = orig & 7, loc = orig >> 3;
  const int qq = nwg >> 3, rr = nwg & 7;
  const int wg = (xcd < rr ? xcd * (qq + 1) : rr * (qq + 1) + (xcd - rr) * qq) + loc;
  const int n0 = (wg % nx) * 128;
  const int m0 = (wg / nx) * BM;

  const int tid = threadIdx.x, lane = tid & 63, w = tid >> 6;
  const int wm = w >> 1, wn = w & 1;
  const int quad = lane >> 4, mr = lane & 15;

  fx4 acc[NF][4] = {};

  auto compute = [&](const short* Ab, const short* Bb) {
#pragma unroll
    for (int ks = 0; ks < 2; ++ks) {
      const int cc = ks * 32 + quad * 8;
      const int swz = cc ^ ((mr & 7) * 8);
      bfx8 af[NF], bf[4];
#pragma unroll
      for (int i = 0; i < NF; ++i)
        af[i] = *(const bfx8*)&Ab[(wm * WTM + i * 16 + mr) * 64 + swz];
#pragma unroll
      for (int j = 0; j < 4; ++j)
        bf[j] = *(const bfx8*)&Bb[(wn * 64 + j * 16 + mr) * 64 + swz];
#pragma unroll
      for (int i = 0; i < NF; ++i)
#pragma unroll
        for (int j = 0; j < 4; ++j)
          acc[i][j] = __builtin_amdgcn_mfma_f32_16x16x32_bf16(af[i], bf[j], acc[i][j], 0, 0, 0);
    }
  };

  if (AT) {
    // reg-staged path (A needs fp32->bf16 cast); single buffer,
    // counted-barrier pipeline (prefetch loads overlap compute).
    const int r0 = tid >> 3;
    const int cs = (tid & 7) * 8;
    const int wswz = cs ^ ((r0 & 7) * 8);
    s16x8 ar[NF], br[4];

    auto loadA = [&](int k0) {
#pragma unroll
      for (int gg = 0; gg < NF; ++gg) {
        const float* p = Ab32 + (long)(m0 + r0 + 32 * gg) * lda + k0 + cs;
        float4 f0 = *(const float4*)p;
        float4 f1 = *(const float4*)(p + 4);
        short o[8] = { f2bf(f0.x), f2bf(f0.y), f2bf(f0.z), f2bf(f0.w),
                       f2bf(f1.x), f2bf(f1.y), f2bf(f1.z), f2bf(f1.w) };
        ar[gg] = *(s16x8*)o;
      }
    };
    auto loadB = [&](int k0) {
#pragma unroll
      for (int hh = 0; hh < 4; ++hh)
        br[hh] = *(const s16x8*)(Wb + (long)(n0 + r0 + 32 * hh) * K + k0 + cs);
    };

    loadA(0); loadB(0);
    for (int k0 = 0; k0 < K; k0 += 64) {
      // prefetched regs ready (first iter: initial loads)
      asm volatile("s_waitcnt vmcnt(0)" ::: "memory");
#pragma unroll
      for (int gg = 0; gg < NF; ++gg)
        *(s16x8*)&As[0][(r0 + 32 * gg) * 64 + wswz] = ar[gg];
#pragma unroll
      for (int hh = 0; hh < 4; ++hh)
        *(s16x8*)&Bs[0][(r0 + 32 * hh) * 64 + wswz] = br[hh];
      asm volatile("s_waitcnt lgkmcnt(0)" ::: "memory");
      __builtin_amdgcn_s_barrier();          // tile visible to all waves
      if (k0 + 64 < K) { loadA(k0 + 64); loadB(k0 + 64); }   // in flight
      compute(&As[0][0], &Bs[0][0]);
      __builtin_amdgcn_s_barrier();          // WAR: reads done before rewrite
    }
  } else {
    // async global_load_lds path, double-buffered, counted vmcnt
    const int lrow = lane >> 3, lcol = lane & 7;

    auto stageA = [&](short* dst, int k0) {
#pragma unroll
      for (int i = 0; i < NF; ++i) {
        const int r = i * 32 + w * 8 + lrow;
        const int swz = (lcol * 8) ^ ((r & 7) * 8);
        gload16(Ab16 + (long)(m0 + r) * lda + k0 + swz,
                dst + (i * 32 + w * 8) * 64);
      }
    };
    auto stageB = [&](short* dst, int k0) {
#pragma unroll
      for (int i = 0; i < 4; ++i) {
        const int r = i * 32 + w * 8 + lrow;
        const int swz = (lcol * 8) ^ ((r & 7) * 8);
        gload16(Wb + (long)(n0 + r) * K + k0 + swz,
                dst + (i * 32 + w * 8) * 64);
      }
    };

    stageA(&As[0][0], 0); stageB(&Bs[0][0], 0);
    const int NT = K >> 6;
    for (int t = 0; t < NT; ++t) {
      const int cur = t & 1;
      if (t + 1 < NT) {
        stageA(&As[cur ^ 1][0], (t + 1) * 64);
        stageB(&Bs[cur ^ 1][0], (t + 1) * 64);
        if constexpr (BM == 128)
          asm volatile("s_waitcnt vmcnt(8)" ::: "memory");  // next tile in flight
        else
          asm volatile("s_waitcnt vmcnt(6)" ::: "memory");  // 2A+4B in flight
      } else {
        asm volatile("s_waitcnt vmcnt(0)" ::: "memory");
      }
      __builtin_amdgcn_s_barrier();
      compute(&As[cur][0], &Bs[cur][0]);
      __builtin_amdgcn_s_barrier();    // all reads of buf[cur] consumed
    }
  }

  float* Cf = (float*)C + (long)z * sC;
  short* Cs = (short*)C + (long)z * sC;
#pragma unroll
  for (int j = 0; j < 4; ++j) {
    const int col = n0 + wn * 64 + j * 16 + mr;
    const float bvx = bb[col];
#pragma unroll
    for (int i = 0; i < NF; ++i) {
      const int row0 = m0 + wm * WTM + i * 16 + quad * 4;
      if (MODE == 2) {               // u transposed fp32: [g][b][c][t]
        const int rb = row0 >> 11, t0 = row0 & 2047;
        fx4 o;
#pragma unroll
        for (int r = 0; r < 4; ++r) o[r] = acc[i][j][r] + bvx;
        *(fx4*)((float*)xtra + (((long)z * B_ + rb) * GD_ + col) * T_ + t0) = o;
      } else if (MODE == 1 && col >= 512) {   // V -> transposed bf16 buffer
        const int h = (col - 512) >> 6, hd = (col - 512) & 63;
        const int rb = row0 >> 11, t0 = row0 & 2047;
        short o4[4];
#pragma unroll
        for (int r = 0; r < 4; ++r) o4[r] = f2bf(acc[i][j][r] + bvx);
        *(short4*)((short*)xtra + ((((long)z * B_ + rb) * NH_ + h) * HD_ + hd) * T_ + t0) =
            *(short4*)o4;
      } else {
        const float sc = (MODE == 1 && col < 256) ? QSCALE : 1.0f;
#pragma unroll
        for (int r = 0; r < 4; ++r) {
          float v = (acc[i][j][r] + bvx) * sc;
          if (OBF) Cs[(long)(row0 + r) * ldc + col] = f2bf(v);
          else     Cf[(long)(row0 + r) * ldc + col] = v;
        }
      }
    }
  }
}

// ---------------------------------------------------------------------------
// x fp32 -> bf16 conversion (one pass; lets gemm1 use the non-AT path with
// half the A-traffic and zero staging VALU).  8 elems/thread, vectorized.
// ---------------------------------------------------------------------------
__global__ __launch_bounds__(256) void cvt_kernel(
    const float* __restrict__ x, short* __restrict__ xb)
{
  const size_t i = ((size_t)blockIdx.x * 256 + threadIdx.x) * 8;
  float4 f0 = *(const float4*)(x + i);
  float4 f1 = *(const float4*)(x + i + 4);
  short o[8] = { f2bf(f0.x), f2bf(f0.y), f2bf(f0.z), f2bf(f0.w),
                 f2bf(f1.x), f2bf(f1.y), f2bf(f1.z), f2bf(f1.w) };
  *(s16x8*)(xb + i) = *(s16x8*)o;
}

// ---------------------------------------------------------------------------
// MFMA flash attention v8 (reverted from v9; best measured variant):
// QBLK=64, 1536 blocks, single-buffered K/V (29 KB LDS -> 5 blocks/CU),
// swapped QK^T, cvt_pk P-pack, 128B-stride XOR-swizzled Ps, reg-staged K/V
// prefetch.  Vs rows 64..79 = bf16 1.0: 5th PV B-tile = denominator l.
// (v9's K/V dbuf + 1-barrier cut occupancy 33->26% and was net-negative.)
// ---------------------------------------------------------------------------
__global__ __launch_bounds__(256) void flash_attn_mfma(
    short* __restrict__ qkv, const short* __restrict__ vtb)
{
  __shared__ short Ks[64][72];    // [kv row][hd]
  __shared__ short Vs[80][72];    // [hd][kv]; rows 64..79 = 1.0bf16 (ones)
  __shared__ short Ps[64 * 64];   // [q row][kv col], stride 128 B, swizzled

  const int bid = blockIdx.x;
  const int Q = 31 - (bid / 48);           // heavy blocks first
  const int combo = bid % 48;
  const int g = combo % 3, bh = combo / 3;
  const int b = bh >> 2, h = bh & 3;

  short* base = qkv + ((size_t)g * M_ + (size_t)b * T_) * D_;
  short*       Qp = base + h * HD_;        // also O destination
  const short* Kp = base + GD_ + h * HD_;
  const short* Vtp = vtb + ((((size_t)g * B_ + b) * NH_ + h) * HD_) * T_;

  const int tid = threadIdx.x, lane = tid & 63, w = tid >> 6;
  const int quad = lane >> 4, mr = lane & 15;
  const int q0 = Q * 64, wr = w * 16;

  const int sra = tid >> 3, sc = (tid & 7) * 8;   // staging rows sra, sra+32

  // ones rows 64..79 of Vs (1024 shorts = 128 chunks), written once pre-loop
  if (tid < 128) {
    const short ov = 0x3F80;
    s16x8 one = { ov, ov, ov, ov, ov, ov, ov, ov };
    *(s16x8*)&Vs[64 + (tid >> 3)][(tid & 7) * 8] = one;
  }

  // Q fragment: aq[ks], row q0+wr+mr (used as B-operand: identical lane
  // layout to A for 16x16x32, so swapping mfma args computes S^T)
  bfx8 aq[2];
#pragma unroll
  for (int ks = 0; ks < 2; ++ks)
    aq[ks] = *(const bfx8*)(Qp + (size_t)(q0 + wr + mr) * D_ +
                            ks * 32 + quad * 8);

  // prefetch tile 0 into regs (all 16B vector loads)
  s16x8 kreg0 = *(const s16x8*)(Kp + (size_t)sra * D_ + sc);
  s16x8 kreg1 = *(const s16x8*)(Kp + (size_t)(sra + 32) * D_ + sc);
  s16x8 vreg0 = *(const s16x8*)(Vtp + (size_t)sra * T_ + sc);
  s16x8 vreg1 = *(const s16x8*)(Vtp + (size_t)(sra + 32) * T_ + sc);

  fx4 Oa[5] = {};    // 4 O-tiles + 1 l-tile

  char* PsB = (char*)&Ps[0];
  const int rot = (mr & 7) << 4;           // XOR swizzle (row&7)<<4; row&7==mr&7

  for (int kt = 0; kt <= Q; ++kt) {
    // regs (tile kt) -> LDS
    *(s16x8*)&Ks[sra][sc]      = kreg0;
    *(s16x8*)&Ks[sra + 32][sc] = kreg1;
    *(s16x8*)&Vs[sra][sc]      = vreg0;
    *(s16x8*)&Vs[sra + 32][sc] = vreg1;
    __syncthreads();

    // prefetch tile kt+1 (in flight during compute below)
    if (kt < Q) {
      const int kn = (kt + 1) * 64;
      kreg0 = *(const s16x8*)(Kp + (size_t)(kn + sra) * D_ + sc);
      kreg1 = *(const s16x8*)(Kp + (size_t)(kn + sra + 32) * D_ + sc);
      vreg0 = *(const s16x8*)(Vtp + (size_t)sra * T_ + kn + sc);
      vreg1 = *(const s16x8*)(Vtp + (size_t)(sra + 32) * T_ + kn + sc);
    }

    // S^T = K Q^T: lane holds q col = mr, kv rows = jj*16 + quad*4 + r
    fx4 st[4] = {};
#pragma unroll
    for (int ks = 0; ks < 2; ++ks) {
      bfx8 bk[4];
#pragma unroll
      for (int jj = 0; jj < 4; ++jj)
        bk[jj] = *(const bfx8*)&Ks[jj * 16 + mr][ks * 32 + quad * 8];
#pragma unroll
      for (int jj = 0; jj < 4; ++jj)
        st[jj] = __builtin_amdgcn_mfma_f32_16x16x32_bf16(bk[jj], aq[ks], st[jj], 0, 0, 0);
    }

    // causal mask (only the diagonal tile kt==Q can cross)
    if (kt == Q) {
      const int qg = q0 + wr + mr;
#pragma unroll
      for (int jj = 0; jj < 4; ++jj) {
        const int kvg0 = kt * 64 + jj * 16 + quad * 4;
#pragma unroll
        for (int r = 0; r < 4; ++r)
          if (kvg0 + r > qg) st[jj][r] = -1e30f;
      }
    }

    // p = exp2(s): pack pairs with v_cvt_pk_bf16_f32, one b64 store per jj.
    // Row = wr+mr (wave-private), kb = (jj*32+quad*8)^rot.
    {
      const int rowb = (wr + mr) << 7;
#pragma unroll
      for (int jj = 0; jj < 4; ++jj) {
        float e0 = exp2f(st[jj][0]);
        float e1 = exp2f(st[jj][1]);
        float e2 = exp2f(st[jj][2]);
        float e3 = exp2f(st[jj][3]);
        unsigned pk0 = cvt_pk_bf16(e0, e1);
        unsigned pk1 = cvt_pk_bf16(e2, e3);
        unsigned long long pv = (unsigned long long)pk0 |
                                ((unsigned long long)pk1 << 32);
        const int kb = (jj * 32 + quad * 8) ^ rot;
        *(unsigned long long*)(PsB + rowb + kb) = pv;
      }
    }

    // O += P @ V ; l += P @ ones (5th tile)
#pragma unroll
    for (int ks = 0; ks < 2; ++ks) {
      const int rowb = (wr + mr) << 7;
      const int kb = (ks * 64 + quad * 16) ^ rot;
      bfx8 ap = *(const bfx8*)(PsB + rowb + kb);
#pragma unroll
      for (int j = 0; j < 5; ++j) {
        bfx8 bv = *(const bfx8*)&Vs[j * 16 + mr][ks * 32 + quad * 8];
        Oa[j] = __builtin_amdgcn_mfma_f32_16x16x32_bf16(ap, bv, Oa[j], 0, 0, 0);
      }
    }
    __syncthreads();   // all waves done reading Ks/Vs before next overwrite
  }

  // epilogue: normalize by l (= Oa[4], same C-layout rows), write O
#pragma unroll
  for (int r = 0; r < 4; ++r) {
    const float inv = 1.0f / Oa[4][r];
    const int row = q0 + wr + quad * 4 + r;
#pragma unroll
    for (int j = 0; j < 4; ++j)
      Qp[(size_t)row * D_ + j * 16 + mr] = f2bf(Oa[j][r] * inv);
  }
}

// ---------------------------------------------------------------------------
// PDE v4 (unchanged from R9): 2 waves/row, halo via shfl + tiny LDS buffer.
// ---------------------------------------------------------------------------
__device__ __forceinline__ float fhj(float x) { return x - x * x + x * x * x; }

__global__ __launch_bounds__(256) void pde_kernel(
    const float* __restrict__ ut, short* __restrict__ ubt)
{
  __shared__ float halo[3][2][4];  // [phase][channel][t1022,t1023,t1024,t1025]

  const int cg = blockIdx.x, b = blockIdx.y, g = blockIdx.z;
  const int tid = threadIdx.x, w = tid >> 6, lane = tid & 63;
  const int c = w >> 1, half = w & 1;
  const int t0 = half * 1024 + lane * 16;
  const float dt = 0.05f;

  const float* src = ut + (((size_t)g * B_ + b) * GD_ + cg * 2 + c) * T_ + t0;

  // register window: uc[2+i] = u[t0+i], i in [0,16); uc[0..1]/uc[18..19] halo
  float uc[20];
#pragma unroll
  for (int q = 0; q < 4; ++q)
    *(fx4*)&uc[2 + q * 4] = *(const fx4*)(src + q * 4);

  // initial halo: intra-wave shfl + inter-wave LDS (phase 0)
  {
    float h0 = __shfl_up(uc[16], 1);    // lane-1's t0+14 = t0-2
    float h1 = __shfl_up(uc[17], 1);    // t0-1
    float h2 = __shfl_down(uc[2], 1);   // t0+16
    float h3 = __shfl_down(uc[3], 1);   // t0+17
    if (half == 0 && lane == 63) { halo[0][c][0] = uc[16]; halo[0][c][1] = uc[17]; }
    if (half == 1 && lane == 0)  { halo[0][c][2] = uc[2];  halo[0][c][3] = uc[3]; }
    __syncthreads();
    uc[0] = h0; uc[1] = h1; uc[18] = h2; uc[19] = h3;
    if (lane == 0) {
      if (half == 1) { uc[0] = halo[0][c][0]; uc[1] = halo[0][c][1]; }
      else           { uc[0] = 0.f;           uc[1] = 0.f; }
    }
    if (lane == 63) {
      if (half == 0) { uc[18] = halo[0][c][2]; uc[19] = halo[0][c][3]; }
      else           { uc[18] = 0.f;           uc[19] = 0.f; }
    }
  }

  float wreg[16];
#pragma unroll
  for (int i = 0; i < 16; ++i) wreg[i] = 0.f;

  for (int step = 0; step < 3; ++step) {
    float nu[16];
#pragma unroll
    for (int tt = 0; tt < 16; ++tt) {
      float um2 = uc[tt], um1 = uc[tt + 1], u = uc[tt + 2];
      float up1 = uc[tt + 3], up2 = uc[tt + 4];
      if (g == 0) {
        float d2 = up1 - 2.f * u + um1;
        wreg[tt] += dt * (d2 - __sinf(u));
        nu[tt] = u + dt * wreg[tt];
      } else if (g == 1) {
        float d1 = 0.5f * (up1 - um1);
        float d3 = 0.5f * (up2 - 2.f * up1 + 2.f * um1 - um2);
        nu[tt] = u + dt * (-6.f * u * d1 - d3);
      } else {
        float d2f = fhj(up1) - 2.f * fhj(u) + fhj(um1);
        float d4  = up2 - 4.f * up1 + 6.f * u - 4.f * um1 + um2;
        wreg[tt] += dt * (d2f - 0.05f * d4);
        nu[tt] = u + dt * wreg[tt];
      }
    }
    if (step < 2) {
      // halo exchange for next step (phase step+1)
      float h0 = __shfl_up(nu[14], 1);
      float h1 = __shfl_up(nu[15], 1);
      float h2 = __shfl_down(nu[0], 1);
      float h3 = __shfl_down(nu[1], 1);
      if (half == 0 && lane == 63) { halo[step + 1][c][0] = nu[14]; halo[step + 1][c][1] = nu[15]; }
      if (half == 1 && lane == 0)  { halo[step + 1][c][2] = nu[0];  halo[step + 1][c][3] = nu[1]; }
      __syncthreads();
      uc[0] = h0; uc[1] = h1; uc[18] = h2; uc[19] = h3;
      if (lane == 0) {
        if (half == 1) { uc[0] = halo[step + 1][c][0]; uc[1] = halo[step + 1][c][1]; }
        else           { uc[0] = 0.f;                  uc[1] = 0.f; }
      }
      if (lane == 63) {
        if (half == 0) { uc[18] = halo[step + 1][c][2]; uc[19] = halo[step + 1][c][3]; }
        else           { uc[18] = 0.f;                  uc[19] = 0.f; }
      }
    }
#pragma unroll
    for (int i = 0; i < 16; ++i) uc[2 + i] = nu[i];
  }

  // coalesced bf16 write: lane's 16 t contiguous (32 B)
  short o16[16];
#pragma unroll
  for (int i = 0; i < 16; ++i) o16[i] = f2bf(uc[2 + i]);
  short* dst = ubt + (((size_t)g * B_ + b) * GD_ + cg * 2 + c) * T_ + t0;
#pragma unroll
  for (int q = 0; q < 2; ++q)
    *(s16x8*)(dst + q * 8) = *(s16x8*)&o16[q * 8];
}

// ---------------------------------------------------------------------------
// Transpose ubt [g][b][c][t] bf16 -> ub16 [b][t][768] (col = g*256+c).
// 32c x 256t LDS tiles (unchanged).
// ---------------------------------------------------------------------------
__global__ __launch_bounds__(256) void transp_kernel(
    const short* __restrict__ ubt, short* __restrict__ ub)
{
  __shared__ short Ls[32][264];   // 264: 16B-aligned rows, bank-spread

  const int tt = blockIdx.x;      // t-tile (256 t)
  const int ct = blockIdx.y;      // c-tile (32 c)
  const int z  = blockIdx.z;      // g*4+b
  const int g = z >> 2, b = z & 3;
  const int tid = threadIdx.x;
  const int c0 = ct * 32, t0 = tt * 256;

  const short* src = ubt + (((size_t)g * B_ + b) * GD_ + c0) * T_ + t0;
#pragma unroll
  for (int it = 0; it < 4; ++it) {
    const int row = (tid >> 5) + it * 8;
    const int col = (tid & 31) * 8;
    *(s16x8*)&Ls[row][col] = *(const s16x8*)(src + (size_t)row * T_ + col);
  }
  __syncthreads();

  short* dst = ub + (size_t)b * T_ * D_ + g * GD_ + c0;
  const int cq = tid & 7, tr = tid >> 3;   // tr in [0,32)
#pragma unroll
  for (int p = 0; p < 8; ++p) {
    const int tl = p * 32 + tr;
    short o4[4];
#pragma unroll
    for (int i = 0; i < 4; ++i) o4[i] = Ls[cq * 4 + i][tl];
    *(short4*)(dst + (size_t)(t0 + tl) * D_ + cq * 4) = *(short4*)o4;
  }
}

// ---------------------------------------------------------------------------
// Prep: the 8 weight transposes (fp32 [K][N] -> bf16 W^T [N][K]) in one launch.
// ---------------------------------------------------------------------------
struct PrepArgs {
  const float* w[8]; short* wt[8];
  int K[8], N[8];
  int tend[8];
};

__global__ __launch_bounds__(256) void prep_kernel(PrepArgs pa)
{
  const int bid = blockIdx.x, tid = threadIdx.x;
  __shared__ float Ws[32][33];
  int ti = 0;
#pragma unroll
  for (int i = 0; i < 8; ++i) if (bid >= pa.tend[i]) ti = i + 1;
  const int tloc = bid - (ti ? pa.tend[ti - 1] : 0);
  const int K = pa.K[ti], N = pa.N[ti];
  const int ntx = N >> 5;
  const int k0 = (tloc / ntx) * 32, n0 = (tloc % ntx) * 32;
  const float* W = pa.w[ti];
  short* WT = pa.wt[ti];
  const int tx = tid & 31, ty = tid >> 5;

#pragma unroll
  for (int i = 0; i < 4; ++i)
    Ws[ty + 8 * i][tx] = W[(long)(k0 + ty + 8 * i) * N + n0 + tx];
  __syncthreads();
#pragma unroll
  for (int i = 0; i < 4; ++i) {
    int r = ty + 8 * i;
    WT[(long)(n0 + r) * K + k0 + tx] = f2bf(Ws[tx][r]);
  }
}

// ---------------------------------------------------------------------------
// Launch.
// ---------------------------------------------------------------------------
extern "C" void kernel_launch(void* const* d_in, const int* in_sizes, int n_in,
                              void* d_out, int out_size, void* d_ws, size_t ws_size,
                              hipStream_t stream)
{
  (void)in_sizes; (void)n_in; (void)out_size; (void)ws_size;

  const float* x         = (const float*)d_in[0];
  const float* in_w      = (const float*)d_in[1];
  const float* in_b      = (const float*)d_in[2];
  const float* sg_qkv_w  = (const float*)d_in[3];
  const float* sg_qkv_b  = (const float*)d_in[4];
  const float* sg_out_w  = (const float*)d_in[5];
  const float* sg_out_b  = (const float*)d_in[6];
  const float* kdv_qkv_w = (const float*)d_in[7];
  const float* kdv_qkv_b = (const float*)d_in[8];
  const float* kdv_out_w = (const float*)d_in[9];
  const float* kdv_out_b = (const float*)d_in[10];
  const float* hj_qkv_w  = (const float*)d_in[11];
  const float* hj_qkv_b  = (const float*)d_in[12];
  const float* hj_out_w  = (const float*)d_in[13];
  const float* hj_out_b  = (const float*)d_in[14];
  const float* out_w     = (const float*)d_in[15];
  const float* out_b     = (const float*)d_in[16];
  float* out = (float*)d_out;

  const size_t MD = (size_t)M_ * D_;     // 6291456
  short* base = (short*)d_ws;
  short* xb   = base;                    // bf16 x (first half of u_t region;
                                         // dead until gemm4 writes uf)
  short* hb   = base + MD;               // h (bf16), second half of u_t region
  float* uf   = (float*)d_ws;            // u_t fp32 overlays [base, hb+MD)
  short* qkvb = base + 2 * MD;
  short* ub16 = qkvb + 3 * MD;
  short* wts  = ub16 + MD;
  short* in_wT  = wts;
  short* qkvT0  = in_wT + 589824;
  short* qkvT1  = qkvT0 + 196608;
  short* qkvT2  = qkvT1 + 196608;
  short* outT0  = qkvT2 + 196608;
  short* outT1  = outT0 + 65536;
  short* outT2  = outT1 + 65536;
  short* out_wT = outT2 + 65536;
  short* vtb    = out_wT + 589824;       // [g][b][h][hd][t], MD shorts
  short* ubt    = qkvb;                  // reuse: qkv dead after gemm4

  dim3 blk(256);

  // --- prep: weight transposes + x -> bf16 ---
  PrepArgs pa;
  const float* wsrc[8] = { in_w, sg_qkv_w, kdv_qkv_w, hj_qkv_w,
                           sg_out_w, kdv_out_w, hj_out_w, out_w };
  short* wdst[8] = { in_wT, qkvT0, qkvT1, qkvT2, outT0, outT1, outT2, out_wT };
  int Ksz[8] = { 768, 256, 256, 256, 256, 256, 256, 768 };
  int Nsz[8] = { 768, 768, 768, 768, 256, 256, 256, 768 };
  int cum = 0;
  for (int i = 0; i < 8; ++i) {
    pa.w[i] = wsrc[i]; pa.wt[i] = wdst[i]; pa.K[i] = Ksz[i]; pa.N[i] = Nsz[i];
    cum += (Ksz[i] >> 5) * (Nsz[i] >> 5);
    pa.tend[i] = cum;
  }
  prep_kernel<<<dim3((unsigned)cum), blk, 0, stream>>>(pa);
  cvt_kernel<<<dim3((unsigned)(MD / 2048)), blk, 0, stream>>>(x, xb);

  // 1) h = xb @ in_w + in_b  (bf16 A, non-AT gload_lds path) -> bf16, BM=64
  gemm_mfma<0, 1, 0, 64><<<dim3(6, 128, 1), blk, 0, stream>>>(
      xb, 0, D_, PW{in_wT, in_wT, in_wT}, PB{in_b, in_b, in_b}, D_,
      hb, 0, D_, nullptr);

  // 2) qkv[g] = h[:,g*256:+256] @ qkv_w_g + b  x3 -> bf16, BM=64 (2304 blk)
  //    Q cols pre-scaled by QSCALE; V cols -> vtb transposed
  gemm_mfma<0, 1, 1, 64><<<dim3(6, 128, 3), blk, 0, stream>>>(
      hb, 256, D_,
      PW{qkvT0, qkvT1, qkvT2}, PB{sg_qkv_b, kdv_qkv_b, hj_qkv_b}, GD_,
      qkvb, (long)MD, D_, vtb);

  // 3) causal MFMA flash attention v8 (64 q-rows/block, 1536 blocks)
  flash_attn_mfma<<<dim3(1536), blk, 0, stream>>>(qkvb, vtb);

  // 4) u_t = (O_g @ out_w_g + b)^T x3 -> fp32 transposed, BM=64 (768 blk)
  gemm_mfma<0, 0, 2, 64><<<dim3(2, 128, 3), blk, 0, stream>>>(
      qkvb, (long)MD, D_,
      PW{outT0, outT1, outT2}, PB{sg_out_b, kdv_out_b, hj_out_b}, GD_,
      uf, 0, 0, uf);

  // 5) PDE on u_t -> ubt bf16 [g][b][c][t] (2 waves/row, 1536 blocks)
  pde_kernel<<<dim3(128, 4, 3), blk, 0, stream>>>(uf, ubt);

  // 5b) transpose ubt -> ub16 [b][t][768]
  transp_kernel<<<dim3(8, 8, 12), blk, 0, stream>>>(ubt, ub16);

  // 6) out = u @ out_w + out_b  (8192x768x768) -> fp32, BM=64 (768 blk)
  gemm_mfma<0, 0, 0, 64><<<dim3(6, 128, 1), blk, 0, stream>>>(
      ub16, 0, D_, PW{out_wT, out_wT, out_wT}, PB{out_b, out_b, out_b}, D_,
      out, 0, D_, nullptr);
}

// Round 16
// 252.272 us; speedup vs baseline: 1.0212x; 1.0212x over previous
//
#include <hip/hip_runtime.h>
#include <math.h>

// Problem constants (fixed by setup_inputs)
#define B_   4
#define T_   2048
#define D_   768
#define M_   8192      // B*T
#define GD_  256
#define NH_  4
#define HD_  64

typedef short  s16x8 __attribute__((ext_vector_type(8)));
typedef __bf16 bfx8  __attribute__((ext_vector_type(8)));
typedef float  fx4   __attribute__((ext_vector_type(4)));

#define LOG2E 1.44269504088896f
#define QSCALE (0.125f * LOG2E)      // folded into Q at qkv-GEMM epilogue

__device__ __forceinline__ short f2bf(float f) {   // round-to-nearest-even
  union { float f; unsigned u; } v; v.f = f;
  unsigned r = v.u + 0x7fffu + ((v.u >> 16) & 1u);
  return (short)(r >> 16);
}

__device__ __forceinline__ unsigned cvt_pk_bf16(float lo, float hi) {
  // dword = { bf16(lo) in [15:0], bf16(hi) in [31:16] }
  unsigned r;
  asm("v_cvt_pk_bf16_f32 %0, %1, %2" : "=v"(r) : "v"(lo), "v"(hi));
  return r;
}

// async global -> LDS, 16 B per lane; lds base must be wave-uniform,
// global address is per-lane (pre-swizzled source pattern).
__device__ __forceinline__ void gload16(const void* g, void* l) {
  __builtin_amdgcn_global_load_lds(
      (const __attribute__((address_space(1))) unsigned int*)g,
      (__attribute__((address_space(3))) unsigned int*)l, 16, 0, 0);
}

struct PW { const short* p0; const short* p1; const short* p2; };
struct PB { const float* p0; const float* p1; const float* p2; };
__device__ __forceinline__ const short* selw(const PW& s, int z) {
  return z == 0 ? s.p0 : (z == 1 ? s.p1 : s.p2);
}
__device__ __forceinline__ const float* selb(const PB& s, int z) {
  return z == 0 ? s.p0 : (z == 1 ? s.p1 : s.p2);
}

// ---------------------------------------------------------------------------
// bf16 MFMA GEMM v5 (unchanged from R15): BM templated, BN=128, BK=64,
// 4 waves (2x2), wave tile (BM/2)x64, acc [BM/32][4], bijective XCD swizzle,
// XOR-swizzled LDS.  Non-AT: global_load_lds + dbuf + counted vmcnt.
// AT: reg-staged counted-barrier pipeline (unused; x pre-converted).
// MODE: 0 plain | 1 qkv | 2 u^T.
// ---------------------------------------------------------------------------
template<int AT, int OBF, int MODE, int BM>
__global__ __launch_bounds__(256) void gemm_mfma(
    const void* __restrict__ Avoid, long sA, int lda,
    PW Wp, PB Bp, int K,
    void* __restrict__ C, long sC, int ldc,
    void* __restrict__ xtra)
{
  constexpr int NF = BM / 32;        // A row-frags per wave (2 or 4)
  constexpr int WTM = BM / 2;        // wave tile M
  __shared__ short As[2][BM * 64];
  __shared__ short Bs[AT ? 1 : 2][128 * 64];

  const int z = blockIdx.z;
  const short* Ab16 = (const short*)Avoid + (long)z * sA;
  const float* Ab32 = (const float*)Avoid + (long)z * sA;
  const short* Wb = selw(Wp, z);
  const float* bb = selb(Bp, z);

  // flatten + bijective XCD swizzle (nwg need not be %8)
  const int nx = gridDim.x, nwg = nx * gridDim.y;
  const int orig = blockIdx.y * nx + blockIdx.x;
  const int xcd = orig & 7, loc = orig >> 3;
  const int qq = nwg >> 3, rr = nwg & 7;
  const int wg = (xcd < rr ? xcd * (qq + 1) : rr * (qq + 1) + (xcd - rr) * qq) + loc;
  const int n0 = (wg % nx) * 128;
  const int m0 = (wg / nx) * BM;

  const int tid = threadIdx.x, lane = tid & 63, w = tid >> 6;
  const int wm = w >> 1, wn = w & 1;
  const int quad = lane >> 4, mr = lane & 15;

  fx4 acc[NF][4] = {};

  auto compute = [&](const short* Ab, const short* Bb) {
#pragma unroll
    for (int ks = 0; ks < 2; ++ks) {
      const int cc = ks * 32 + quad * 8;
      const int swz = cc ^ ((mr & 7) * 8);
      bfx8 af[NF], bf[4];
#pragma unroll
      for (int i = 0; i < NF; ++i)
        af[i] = *(const bfx8*)&Ab[(wm * WTM + i * 16 + mr) * 64 + swz];
#pragma unroll
      for (int j = 0; j < 4; ++j)
        bf[j] = *(const bfx8*)&Bb[(wn * 64 + j * 16 + mr) * 64 + swz];
#pragma unroll
      for (int i = 0; i < NF; ++i)
#pragma unroll
        for (int j = 0; j < 4; ++j)
          acc[i][j] = __builtin_amdgcn_mfma_f32_16x16x32_bf16(af[i], bf[j], acc[i][j], 0, 0, 0);
    }
  };

  if (AT) {
    // reg-staged path (A needs fp32->bf16 cast); single buffer,
    // counted-barrier pipeline (prefetch loads overlap compute).
    const int r0 = tid >> 3;
    const int cs = (tid & 7) * 8;
    const int wswz = cs ^ ((r0 & 7) * 8);
    s16x8 ar[NF], br[4];

    auto loadA = [&](int k0) {
#pragma unroll
      for (int gg = 0; gg < NF; ++gg) {
        const float* p = Ab32 + (long)(m0 + r0 + 32 * gg) * lda + k0 + cs;
        float4 f0 = *(const float4*)p;
        float4 f1 = *(const float4*)(p + 4);
        short o[8] = { f2bf(f0.x), f2bf(f0.y), f2bf(f0.z), f2bf(f0.w),
                       f2bf(f1.x), f2bf(f1.y), f2bf(f1.z), f2bf(f1.w) };
        ar[gg] = *(s16x8*)o;
      }
    };
    auto loadB = [&](int k0) {
#pragma unroll
      for (int hh = 0; hh < 4; ++hh)
        br[hh] = *(const s16x8*)(Wb + (long)(n0 + r0 + 32 * hh) * K + k0 + cs);
    };

    loadA(0); loadB(0);
    for (int k0 = 0; k0 < K; k0 += 64) {
      asm volatile("s_waitcnt vmcnt(0)" ::: "memory");
#pragma unroll
      for (int gg = 0; gg < NF; ++gg)
        *(s16x8*)&As[0][(r0 + 32 * gg) * 64 + wswz] = ar[gg];
#pragma unroll
      for (int hh = 0; hh < 4; ++hh)
        *(s16x8*)&Bs[0][(r0 + 32 * hh) * 64 + wswz] = br[hh];
      asm volatile("s_waitcnt lgkmcnt(0)" ::: "memory");
      __builtin_amdgcn_s_barrier();          // tile visible to all waves
      if (k0 + 64 < K) { loadA(k0 + 64); loadB(k0 + 64); }   // in flight
      compute(&As[0][0], &Bs[0][0]);
      __builtin_amdgcn_s_barrier();          // WAR: reads done before rewrite
    }
  } else {
    // async global_load_lds path, double-buffered, counted vmcnt
    const int lrow = lane >> 3, lcol = lane & 7;

    auto stageA = [&](short* dst, int k0) {
#pragma unroll
      for (int i = 0; i < NF; ++i) {
        const int r = i * 32 + w * 8 + lrow;
        const int swz = (lcol * 8) ^ ((r & 7) * 8);
        gload16(Ab16 + (long)(m0 + r) * lda + k0 + swz,
                dst + (i * 32 + w * 8) * 64);
      }
    };
    auto stageB = [&](short* dst, int k0) {
#pragma unroll
      for (int i = 0; i < 4; ++i) {
        const int r = i * 32 + w * 8 + lrow;
        const int swz = (lcol * 8) ^ ((r & 7) * 8);
        gload16(Wb + (long)(n0 + r) * K + k0 + swz,
                dst + (i * 32 + w * 8) * 64);
      }
    };

    stageA(&As[0][0], 0); stageB(&Bs[0][0], 0);
    const int NT = K >> 6;
    for (int t = 0; t < NT; ++t) {
      const int cur = t & 1;
      if (t + 1 < NT) {
        stageA(&As[cur ^ 1][0], (t + 1) * 64);
        stageB(&Bs[cur ^ 1][0], (t + 1) * 64);
        if constexpr (BM == 128)
          asm volatile("s_waitcnt vmcnt(8)" ::: "memory");  // next tile in flight
        else
          asm volatile("s_waitcnt vmcnt(6)" ::: "memory");  // 2A+4B in flight
      } else {
        asm volatile("s_waitcnt vmcnt(0)" ::: "memory");
      }
      __builtin_amdgcn_s_barrier();
      compute(&As[cur][0], &Bs[cur][0]);
      __builtin_amdgcn_s_barrier();    // all reads of buf[cur] consumed
    }
  }

  float* Cf = (float*)C + (long)z * sC;
  short* Cs = (short*)C + (long)z * sC;
#pragma unroll
  for (int j = 0; j < 4; ++j) {
    const int col = n0 + wn * 64 + j * 16 + mr;
    const float bvx = bb[col];
#pragma unroll
    for (int i = 0; i < NF; ++i) {
      const int row0 = m0 + wm * WTM + i * 16 + quad * 4;
      if (MODE == 2) {               // u transposed fp32: [g][b][c][t]
        const int rb = row0 >> 11, t0 = row0 & 2047;
        fx4 o;
#pragma unroll
        for (int r = 0; r < 4; ++r) o[r] = acc[i][j][r] + bvx;
        *(fx4*)((float*)xtra + (((long)z * B_ + rb) * GD_ + col) * T_ + t0) = o;
      } else if (MODE == 1 && col >= 512) {   // V -> transposed bf16 buffer
        const int h = (col - 512) >> 6, hd = (col - 512) & 63;
        const int rb = row0 >> 11, t0 = row0 & 2047;
        short o4[4];
#pragma unroll
        for (int r = 0; r < 4; ++r) o4[r] = f2bf(acc[i][j][r] + bvx);
        *(short4*)((short*)xtra + ((((long)z * B_ + rb) * NH_ + h) * HD_ + hd) * T_ + t0) =
            *(short4*)o4;
      } else {
        const float sc = (MODE == 1 && col < 256) ? QSCALE : 1.0f;
#pragma unroll
        for (int r = 0; r < 4; ++r) {
          float v = (acc[i][j][r] + bvx) * sc;
          if (OBF) Cs[(long)(row0 + r) * ldc + col] = f2bf(v);
          else     Cf[(long)(row0 + r) * ldc + col] = v;
        }
      }
    }
  }
}

// ---------------------------------------------------------------------------
// x fp32 -> bf16 conversion (one pass; gemm1 uses the non-AT path).
// ---------------------------------------------------------------------------
__global__ __launch_bounds__(256) void cvt_kernel(
    const float* __restrict__ x, short* __restrict__ xb)
{
  const size_t i = ((size_t)blockIdx.x * 256 + threadIdx.x) * 8;
  float4 f0 = *(const float4*)(x + i);
  float4 f1 = *(const float4*)(x + i + 4);
  short o[8] = { f2bf(f0.x), f2bf(f0.y), f2bf(f0.z), f2bf(f0.w),
                 f2bf(f1.x), f2bf(f1.y), f2bf(f1.z), f2bf(f1.w) };
  *(s16x8*)(xb + i) = *(s16x8*)o;
}

// ---------------------------------------------------------------------------
// MFMA flash attention v10: 8-wave (512-thread) blocks, QBLK=128.
// Mechanism: K/V staging + barrier events are per-BLOCK-tile; QBLK 64->128
// halves block-tile visits (25344 -> 13056) so staging traffic and barrier
// count halve while per-wave compute (16 q rows) is unchanged.  Each thread
// stages 2x16B (was 4).  LDS 37.1 KB: Ks 64x72, Vs 80x72 (rows 64..79 =
// bf16 1.0 -> 5th PV B-tile = denominator l), Ps 128 rows x 128 B swizzled.
// 768 blocks = 3 blocks/CU -> 24 waves/CU (was ~20).  Waves 0..3 skip the
// final kv tile (barriers stay outside the skip); tiles kt >= 2Q masked.
// Swapped QK^T + cvt_pk P-pack + XOR swizzle carried over from v8.
// ---------------------------------------------------------------------------
__global__ __launch_bounds__(512) void flash_attn_mfma(
    short* __restrict__ qkv, const short* __restrict__ vtb)
{
  __shared__ short Ks[64][72];    // [kv row][hd]
  __shared__ short Vs[80][72];    // [hd][kv]; rows 64..79 = 1.0bf16 (ones)
  __shared__ short Ps[128 * 64];  // [q row][kv col], stride 128 B, swizzled

  const int bid = blockIdx.x;
  const int Q = 15 - (bid / 48);           // heavy blocks first
  const int combo = bid % 48;
  const int g = combo % 3, bh = combo / 3;
  const int b = bh >> 2, h = bh & 3;

  short* base = qkv + ((size_t)g * M_ + (size_t)b * T_) * D_;
  short*       Qp = base + h * HD_;        // also O destination
  const short* Kp = base + GD_ + h * HD_;
  const short* Vtp = vtb + ((((size_t)g * B_ + b) * NH_ + h) * HD_) * T_;

  const int tid = threadIdx.x, lane = tid & 63, w = tid >> 6;   // w in [0,8)
  const int quad = lane >> 4, mr = lane & 15;
  const int q0 = Q * 128, wr = w * 16;
  const int qhi = q0 + wr + 15;            // last q row this wave owns

  const int sra = tid >> 3, sc = (tid & 7) * 8;   // sra in [0,64)

  // ones rows 64..79 of Vs (1024 shorts = 128 chunks), written once pre-loop
  if (tid < 128) {
    const short ov = 0x3F80;
    s16x8 one = { ov, ov, ov, ov, ov, ov, ov, ov };
    *(s16x8*)&Vs[64 + (tid >> 3)][(tid & 7) * 8] = one;
  }

  // Q fragment: aq[ks], row q0+wr+mr (used as B-operand: identical lane
  // layout to A for 16x16x32, so swapping mfma args computes S^T)
  bfx8 aq[2];
#pragma unroll
  for (int ks = 0; ks < 2; ++ks)
    aq[ks] = *(const bfx8*)(Qp + (size_t)(q0 + wr + mr) * D_ +
                            ks * 32 + quad * 8);

  // prefetch tile 0 into regs (one 16B K seg + one 16B V seg per thread)
  s16x8 kreg = *(const s16x8*)(Kp + (size_t)sra * D_ + sc);
  s16x8 vreg = *(const s16x8*)(Vtp + (size_t)sra * T_ + sc);

  fx4 Oa[5] = {};    // 4 O-tiles + 1 l-tile

  char* PsB = (char*)&Ps[0];
  const int rot = (mr & 7) << 4;           // XOR swizzle (row&7)<<4; row&7==mr&7

  const int ktmax = 2 * Q + 1;
  for (int kt = 0; kt <= ktmax; ++kt) {
    // regs (tile kt) -> LDS
    *(s16x8*)&Ks[sra][sc] = kreg;
    *(s16x8*)&Vs[sra][sc] = vreg;
    __syncthreads();

    // prefetch tile kt+1 (in flight during compute below)
    if (kt < ktmax) {
      const int kn = (kt + 1) * 64;
      kreg = *(const s16x8*)(Kp + (size_t)(kn + sra) * D_ + sc);
      vreg = *(const s16x8*)(Vtp + (size_t)sra * T_ + kn + sc);
    }

    // skip tiles fully above the diagonal for this wave's q rows
    if (kt * 64 <= qhi) {
      // S^T = K Q^T: lane holds q col = mr, kv rows = jj*16 + quad*4 + r
      fx4 st[4] = {};
#pragma unroll
      for (int ks = 0; ks < 2; ++ks) {
        bfx8 bk[4];
#pragma unroll
        for (int jj = 0; jj < 4; ++jj)
          bk[jj] = *(const bfx8*)&Ks[jj * 16 + mr][ks * 32 + quad * 8];
#pragma unroll
        for (int jj = 0; jj < 4; ++jj)
          st[jj] = __builtin_amdgcn_mfma_f32_16x16x32_bf16(bk[jj], aq[ks], st[jj], 0, 0, 0);
      }

      // causal mask (only the last two kv tiles can cross the diagonal)
      if (kt >= 2 * Q) {
        const int qg = q0 + wr + mr;
#pragma unroll
        for (int jj = 0; jj < 4; ++jj) {
          const int kvg0 = kt * 64 + jj * 16 + quad * 4;
#pragma unroll
          for (int r = 0; r < 4; ++r)
            if (kvg0 + r > qg) st[jj][r] = -1e30f;
        }
      }

      // p = exp2(s): pack pairs with v_cvt_pk_bf16_f32, one b64 store per jj.
      // Row = wr+mr (wave-private, rows 0..127), kb = (jj*32+quad*8)^rot.
      {
        const int rowb = (wr + mr) << 7;
#pragma unroll
        for (int jj = 0; jj < 4; ++jj) {
          float e0 = exp2f(st[jj][0]);
          float e1 = exp2f(st[jj][1]);
          float e2 = exp2f(st[jj][2]);
          float e3 = exp2f(st[jj][3]);
          unsigned pk0 = cvt_pk_bf16(e0, e1);
          unsigned pk1 = cvt_pk_bf16(e2, e3);
          unsigned long long pv = (unsigned long long)pk0 |
                                  ((unsigned long long)pk1 << 32);
          const int kb = (jj * 32 + quad * 8) ^ rot;
          *(unsigned long long*)(PsB + rowb + kb) = pv;
        }
      }

      // O += P @ V ; l += P @ ones (5th tile)
#pragma unroll
      for (int ks = 0; ks < 2; ++ks) {
        const int rowb = (wr + mr) << 7;
        const int kb = (ks * 64 + quad * 16) ^ rot;
        bfx8 ap = *(const bfx8*)(PsB + rowb + kb);
#pragma unroll
        for (int j = 0; j < 5; ++j) {
          bfx8 bv = *(const bfx8*)&Vs[j * 16 + mr][ks * 32 + quad * 8];
          Oa[j] = __builtin_amdgcn_mfma_f32_16x16x32_bf16(ap, bv, Oa[j], 0, 0, 0);
        }
      }
    }
    __syncthreads();   // all waves done reading Ks/Vs before next overwrite
  }

  // epilogue: normalize by l (= Oa[4], same C-layout rows), write O
#pragma unroll
  for (int r = 0; r < 4; ++r) {
    const float inv = 1.0f / Oa[4][r];
    const int row = q0 + wr + quad * 4 + r;
#pragma unroll
    for (int j = 0; j < 4; ++j)
      Qp[(size_t)row * D_ + j * 16 + mr] = f2bf(Oa[j][r] * inv);
  }
}

// ---------------------------------------------------------------------------
// PDE v4 (unchanged from R9): 2 waves/row, halo via shfl + tiny LDS buffer.
// ---------------------------------------------------------------------------
__device__ __forceinline__ float fhj(float x) { return x - x * x + x * x * x; }

__global__ __launch_bounds__(256) void pde_kernel(
    const float* __restrict__ ut, short* __restrict__ ubt)
{
  __shared__ float halo[3][2][4];  // [phase][channel][t1022,t1023,t1024,t1025]

  const int cg = blockIdx.x, b = blockIdx.y, g = blockIdx.z;
  const int tid = threadIdx.x, w = tid >> 6, lane = tid & 63;
  const int c = w >> 1, half = w & 1;
  const int t0 = half * 1024 + lane * 16;
  const float dt = 0.05f;

  const float* src = ut + (((size_t)g * B_ + b) * GD_ + cg * 2 + c) * T_ + t0;

  // register window: uc[2+i] = u[t0+i], i in [0,16); uc[0..1]/uc[18..19] halo
  float uc[20];
#pragma unroll
  for (int q = 0; q < 4; ++q)
    *(fx4*)&uc[2 + q * 4] = *(const fx4*)(src + q * 4);

  // initial halo: intra-wave shfl + inter-wave LDS (phase 0)
  {
    float h0 = __shfl_up(uc[16], 1);    // lane-1's t0+14 = t0-2
    float h1 = __shfl_up(uc[17], 1);    // t0-1
    float h2 = __shfl_down(uc[2], 1);   // t0+16
    float h3 = __shfl_down(uc[3], 1);   // t0+17
    if (half == 0 && lane == 63) { halo[0][c][0] = uc[16]; halo[0][c][1] = uc[17]; }
    if (half == 1 && lane == 0)  { halo[0][c][2] = uc[2];  halo[0][c][3] = uc[3]; }
    __syncthreads();
    uc[0] = h0; uc[1] = h1; uc[18] = h2; uc[19] = h3;
    if (lane == 0) {
      if (half == 1) { uc[0] = halo[0][c][0]; uc[1] = halo[0][c][1]; }
      else           { uc[0] = 0.f;           uc[1] = 0.f; }
    }
    if (lane == 63) {
      if (half == 0) { uc[18] = halo[0][c][2]; uc[19] = halo[0][c][3]; }
      else           { uc[18] = 0.f;           uc[19] = 0.f; }
    }
  }

  float wreg[16];
#pragma unroll
  for (int i = 0; i < 16; ++i) wreg[i] = 0.f;

  for (int step = 0; step < 3; ++step) {
    float nu[16];
#pragma unroll
    for (int tt = 0; tt < 16; ++tt) {
      float um2 = uc[tt], um1 = uc[tt + 1], u = uc[tt + 2];
      float up1 = uc[tt + 3], up2 = uc[tt + 4];
      if (g == 0) {
        float d2 = up1 - 2.f * u + um1;
        wreg[tt] += dt * (d2 - __sinf(u));
        nu[tt] = u + dt * wreg[tt];
      } else if (g == 1) {
        float d1 = 0.5f * (up1 - um1);
        float d3 = 0.5f * (up2 - 2.f * up1 + 2.f * um1 - um2);
        nu[tt] = u + dt * (-6.f * u * d1 - d3);
      } else {
        float d2f = fhj(up1) - 2.f * fhj(u) + fhj(um1);
        float d4  = up2 - 4.f * up1 + 6.f * u - 4.f * um1 + um2;
        wreg[tt] += dt * (d2f - 0.05f * d4);
        nu[tt] = u + dt * wreg[tt];
      }
    }
    if (step < 2) {
      // halo exchange for next step (phase step+1)
      float h0 = __shfl_up(nu[14], 1);
      float h1 = __shfl_up(nu[15], 1);
      float h2 = __shfl_down(nu[0], 1);
      float h3 = __shfl_down(nu[1], 1);
      if (half == 0 && lane == 63) { halo[step + 1][c][0] = nu[14]; halo[step + 1][c][1] = nu[15]; }
      if (half == 1 && lane == 0)  { halo[step + 1][c][2] = nu[0];  halo[step + 1][c][3] = nu[1]; }
      __syncthreads();
      uc[0] = h0; uc[1] = h1; uc[18] = h2; uc[19] = h3;
      if (lane == 0) {
        if (half == 1) { uc[0] = halo[step + 1][c][0]; uc[1] = halo[step + 1][c][1]; }
        else           { uc[0] = 0.f;                  uc[1] = 0.f; }
      }
      if (lane == 63) {
        if (half == 0) { uc[18] = halo[step + 1][c][2]; uc[19] = halo[step + 1][c][3]; }
        else           { uc[18] = 0.f;                  uc[19] = 0.f; }
      }
    }
#pragma unroll
    for (int i = 0; i < 16; ++i) uc[2 + i] = nu[i];
  }

  // coalesced bf16 write: lane's 16 t contiguous (32 B)
  short o16[16];
#pragma unroll
  for (int i = 0; i < 16; ++i) o16[i] = f2bf(uc[2 + i]);
  short* dst = ubt + (((size_t)g * B_ + b) * GD_ + cg * 2 + c) * T_ + t0;
#pragma unroll
  for (int q = 0; q < 2; ++q)
    *(s16x8*)(dst + q * 8) = *(s16x8*)&o16[q * 8];
}

// ---------------------------------------------------------------------------
// Transpose ubt [g][b][c][t] bf16 -> ub16 [b][t][768] (col = g*256+c).
// 32c x 256t LDS tiles (unchanged).
// ---------------------------------------------------------------------------
__global__ __launch_bounds__(256) void transp_kernel(
    const short* __restrict__ ubt, short* __restrict__ ub)
{
  __shared__ short Ls[32][264];   // 264: 16B-aligned rows, bank-spread

  const int tt = blockIdx.x;      // t-tile (256 t)
  const int ct = blockIdx.y;      // c-tile (32 c)
  const int z  = blockIdx.z;      // g*4+b
  const int g = z >> 2, b = z & 3;
  const int tid = threadIdx.x;
  const int c0 = ct * 32, t0 = tt * 256;

  const short* src = ubt + (((size_t)g * B_ + b) * GD_ + c0) * T_ + t0;
#pragma unroll
  for (int it = 0; it < 4; ++it) {
    const int row = (tid >> 5) + it * 8;
    const int col = (tid & 31) * 8;
    *(s16x8*)&Ls[row][col] = *(const s16x8*)(src + (size_t)row * T_ + col);
  }
  __syncthreads();

  short* dst = ub + (size_t)b * T_ * D_ + g * GD_ + c0;
  const int cq = tid & 7, tr = tid >> 3;   // tr in [0,32)
#pragma unroll
  for (int p = 0; p < 8; ++p) {
    const int tl = p * 32 + tr;
    short o4[4];
#pragma unroll
    for (int i = 0; i < 4; ++i) o4[i] = Ls[cq * 4 + i][tl];
    *(short4*)(dst + (size_t)(t0 + tl) * D_ + cq * 4) = *(short4*)o4;
  }
}

// ---------------------------------------------------------------------------
// Prep: the 8 weight transposes (fp32 [K][N] -> bf16 W^T [N][K]) in one launch.
// ---------------------------------------------------------------------------
struct PrepArgs {
  const float* w[8]; short* wt[8];
  int K[8], N[8];
  int tend[8];
};

__global__ __launch_bounds__(256) void prep_kernel(PrepArgs pa)
{
  const int bid = blockIdx.x, tid = threadIdx.x;
  __shared__ float Ws[32][33];
  int ti = 0;
#pragma unroll
  for (int i = 0; i < 8; ++i) if (bid >= pa.tend[i]) ti = i + 1;
  const int tloc = bid - (ti ? pa.tend[ti - 1] : 0);
  const int K = pa.K[ti], N = pa.N[ti];
  const int ntx = N >> 5;
  const int k0 = (tloc / ntx) * 32, n0 = (tloc % ntx) * 32;
  const float* W = pa.w[ti];
  short* WT = pa.wt[ti];
  const int tx = tid & 31, ty = tid >> 5;

#pragma unroll
  for (int i = 0; i < 4; ++i)
    Ws[ty + 8 * i][tx] = W[(long)(k0 + ty + 8 * i) * N + n0 + tx];
  __syncthreads();
#pragma unroll
  for (int i = 0; i < 4; ++i) {
    int r = ty + 8 * i;
    WT[(long)(n0 + r) * K + k0 + tx] = f2bf(Ws[tx][r]);
  }
}

// ---------------------------------------------------------------------------
// Launch.
// ---------------------------------------------------------------------------
extern "C" void kernel_launch(void* const* d_in, const int* in_sizes, int n_in,
                              void* d_out, int out_size, void* d_ws, size_t ws_size,
                              hipStream_t stream)
{
  (void)in_sizes; (void)n_in; (void)out_size; (void)ws_size;

  const float* x         = (const float*)d_in[0];
  const float* in_w      = (const float*)d_in[1];
  const float* in_b      = (const float*)d_in[2];
  const float* sg_qkv_w  = (const float*)d_in[3];
  const float* sg_qkv_b  = (const float*)d_in[4];
  const float* sg_out_w  = (const float*)d_in[5];
  const float* sg_out_b  = (const float*)d_in[6];
  const float* kdv_qkv_w = (const float*)d_in[7];
  const float* kdv_qkv_b = (const float*)d_in[8];
  const float* kdv_out_w = (const float*)d_in[9];
  const float* kdv_out_b = (const float*)d_in[10];
  const float* hj_qkv_w  = (const float*)d_in[11];
  const float* hj_qkv_b  = (const float*)d_in[12];
  const float* hj_out_w  = (const float*)d_in[13];
  const float* hj_out_b  = (const float*)d_in[14];
  const float* out_w     = (const float*)d_in[15];
  const float* out_b     = (const float*)d_in[16];
  float* out = (float*)d_out;

  const size_t MD = (size_t)M_ * D_;     // 6291456
  short* base = (short*)d_ws;
  short* xb   = base;                    // bf16 x (first half of u_t region;
                                         // dead until gemm4 writes uf)
  short* hb   = base + MD;               // h (bf16), second half of u_t region
  float* uf   = (float*)d_ws;            // u_t fp32 overlays [base, hb+MD)
  short* qkvb = base + 2 * MD;
  short* ub16 = qkvb + 3 * MD;
  short* wts  = ub16 + MD;
  short* in_wT  = wts;
  short* qkvT0  = in_wT + 589824;
  short* qkvT1  = qkvT0 + 196608;
  short* qkvT2  = qkvT1 + 196608;
  short* outT0  = qkvT2 + 196608;
  short* outT1  = outT0 + 65536;
  short* outT2  = outT1 + 65536;
  short* out_wT = outT2 + 65536;
  short* vtb    = out_wT + 589824;       // [g][b][h][hd][t], MD shorts
  short* ubt    = qkvb;                  // reuse: qkv dead after gemm4

  dim3 blk(256);

  // --- prep: weight transposes + x -> bf16 ---
  PrepArgs pa;
  const float* wsrc[8] = { in_w, sg_qkv_w, kdv_qkv_w, hj_qkv_w,
                           sg_out_w, kdv_out_w, hj_out_w, out_w };
  short* wdst[8] = { in_wT, qkvT0, qkvT1, qkvT2, outT0, outT1, outT2, out_wT };
  int Ksz[8] = { 768, 256, 256, 256, 256, 256, 256, 768 };
  int Nsz[8] = { 768, 768, 768, 768, 256, 256, 256, 768 };
  int cum = 0;
  for (int i = 0; i < 8; ++i) {
    pa.w[i] = wsrc[i]; pa.wt[i] = wdst[i]; pa.K[i] = Ksz[i]; pa.N[i] = Nsz[i];
    cum += (Ksz[i] >> 5) * (Nsz[i] >> 5);
    pa.tend[i] = cum;
  }
  prep_kernel<<<dim3((unsigned)cum), blk, 0, stream>>>(pa);
  cvt_kernel<<<dim3((unsigned)(MD / 2048)), blk, 0, stream>>>(x, xb);

  // 1) h = xb @ in_w + in_b  (bf16 A, non-AT gload_lds path) -> bf16, BM=64
  gemm_mfma<0, 1, 0, 64><<<dim3(6, 128, 1), blk, 0, stream>>>(
      xb, 0, D_, PW{in_wT, in_wT, in_wT}, PB{in_b, in_b, in_b}, D_,
      hb, 0, D_, nullptr);

  // 2) qkv[g] = h[:,g*256:+256] @ qkv_w_g + b  x3 -> bf16, BM=64 (2304 blk)
  //    Q cols pre-scaled by QSCALE; V cols -> vtb transposed
  gemm_mfma<0, 1, 1, 64><<<dim3(6, 128, 3), blk, 0, stream>>>(
      hb, 256, D_,
      PW{qkvT0, qkvT1, qkvT2}, PB{sg_qkv_b, kdv_qkv_b, hj_qkv_b}, GD_,
      qkvb, (long)MD, D_, vtb);

  // 3) causal MFMA flash attention v10 (128 q-rows/block, 8 waves, 768 blk)
  flash_attn_mfma<<<dim3(768), dim3(512), 0, stream>>>(qkvb, vtb);

  // 4) u_t = (O_g @ out_w_g + b)^T x3 -> fp32 transposed, BM=64 (768 blk)
  gemm_mfma<0, 0, 2, 64><<<dim3(2, 128, 3), blk, 0, stream>>>(
      qkvb, (long)MD, D_,
      PW{outT0, outT1, outT2}, PB{sg_out_b, kdv_out_b, hj_out_b}, GD_,
      uf, 0, 0, uf);

  // 5) PDE on u_t -> ubt bf16 [g][b][c][t] (2 waves/row, 1536 blocks)
  pde_kernel<<<dim3(128, 4, 3), blk, 0, stream>>>(uf, ubt);

  // 5b) transpose ubt -> ub16 [b][t][768]
  transp_kernel<<<dim3(8, 8, 12), blk, 0, stream>>>(ubt, ub16);

  // 6) out = u @ out_w + out_b  (8192x768x768) -> fp32, BM=64 (768 blk)
  gemm_mfma<0, 0, 0, 64><<<dim3(6, 128, 1), blk, 0, stream>>>(
      ub16, 0, D_, PW{out_wT, out_wT, out_wT}, PB{out_b, out_b, out_b}, D_,
      out, 0, D_, nullptr);
}